// Round 5
// baseline (222.768 us; speedup 1.0000x reference)
//
#include <hip/hip_runtime.h>
#include <hip/hip_bf16.h>

#define M_DIM 512
#define HID 7168
#define D_KV_C 512
#define D_Q_C 1536
#define D_R 64
#define D_Q 128
#define D_KV 128
#define H_DIM 16
#define S_KV 4096
#define TOPK 512
#define D_ATT 576
#define SPLIT 2
#define SROWS 256   // TOPK / SPLIT

typedef _Float16 half_t;
typedef __attribute__((ext_vector_type(8))) _Float16 f16x8_t;
typedef __attribute__((ext_vector_type(4))) float f32x4_t;
typedef __attribute__((ext_vector_type(2))) unsigned int u32x2_t;

#define MFMA_F16(a, b, c) __builtin_amdgcn_mfma_f32_16x16x32_f16((a), (b), (c), 0, 0, 0)

__device__ __forceinline__ unsigned lds_addr32(const void* p) {
    return (unsigned)(unsigned long long)(const __attribute__((address_space(3))) char*)p;
}

typedef const __attribute__((address_space(1))) unsigned int* gptr_t;
typedef __attribute__((address_space(3))) unsigned int* lptr_t;
__device__ __forceinline__ void gload_lds16(const void* g, void* l) {
    __builtin_amdgcn_global_load_lds((gptr_t)g, (lptr_t)l, 16, 0, 0);
}

// ---------------- elementwise fp32 -> fp16 ----------------
__global__ __launch_bounds__(256) void cvt_f16(const float* __restrict__ src,
                                               half_t* __restrict__ dst, int n8)
{
    int i = blockIdx.x * 256 + threadIdx.x;
    if (i >= n8) return;
    const float4* s = (const float4*)src + (size_t)i * 2;
    float4 a = s[0], b = s[1];
    f16x8_t o;
    o[0] = (half_t)a.x; o[1] = (half_t)a.y; o[2] = (half_t)a.z; o[3] = (half_t)a.w;
    o[4] = (half_t)b.x; o[5] = (half_t)b.y; o[6] = (half_t)b.z; o[7] = (half_t)b.w;
    *(f16x8_t*)(dst + (size_t)i * 8) = o;
}

// ---------------- sum NS fp32 slices -> fp16 ----------------
template<int NS>
__global__ __launch_bounds__(256) void cvt_sum(const float* __restrict__ src, long long slice,
                                               half_t* __restrict__ dst, int n8)
{
    int i = blockIdx.x * 256 + threadIdx.x;
    if (i >= n8) return;
    float a[8] = {};
    #pragma unroll
    for (int s = 0; s < NS; s++) {
        const float4* p = (const float4*)(src + (size_t)s * slice) + (size_t)i * 2;
        float4 u = p[0], v = p[1];
        a[0] += u.x; a[1] += u.y; a[2] += u.z; a[3] += u.w;
        a[4] += v.x; a[5] += v.y; a[6] += v.z; a[7] += v.w;
    }
    f16x8_t o;
    #pragma unroll
    for (int j = 0; j < 8; j++) o[j] = (half_t)a[j];
    *(f16x8_t*)(dst + (size_t)i * 8) = o;
}

// sum 2 slices of q (512x3072) -> q16, scatter pe cols into qf16 tail
__global__ __launch_bounds__(256) void cvt_sum_q(const float* __restrict__ src, long long slice,
                                                 half_t* __restrict__ q16, half_t* __restrict__ qf)
{
    int i = blockIdx.x * 256 + threadIdx.x;
    if (i >= M_DIM * 3072 / 8) return;
    float a[8] = {};
    #pragma unroll
    for (int s = 0; s < 2; s++) {
        const float4* p = (const float4*)(src + (size_t)s * slice) + (size_t)i * 2;
        float4 u = p[0], v = p[1];
        a[0] += u.x; a[1] += u.y; a[2] += u.z; a[3] += u.w;
        a[4] += v.x; a[5] += v.y; a[6] += v.z; a[7] += v.w;
    }
    f16x8_t o;
    #pragma unroll
    for (int j = 0; j < 8; j++) o[j] = (half_t)a[j];
    *(f16x8_t*)(q16 + (size_t)i * 8) = o;
    int col = (i * 8) % 3072;
    int c = col % 192;                 // within-head col; blocks of 8 never straddle
    if (c >= 128) {
        int row = (i * 8) / 3072, h = col / 192;
        int mh = row * 16 + h;
        *(f16x8_t*)(qf + (size_t)mh * D_ATT + D_KV_C + (c - 128)) = o;
    }
}

// ---------------- transpose-convert fp32 [K][ld] -> fp16 [N][K] ----------------
__global__ __launch_bounds__(256) void cvt_t(
    const float* __restrict__ src, int ld_src, long long sS,
    half_t* __restrict__ dst, int ld_dst, long long sD)
{
    src += (size_t)blockIdx.z * sS;
    dst += (size_t)blockIdx.z * sD;
    int k0 = blockIdx.y * 64, n0 = blockIdx.x * 64;
    __shared__ half_t t[64][80];
    int tid = threadIdx.x;
    int kr = tid >> 4, nc = (tid & 15) * 4;
    #pragma unroll
    for (int i = 0; i < 4; i++) {
        float4 v = *(const float4*)&src[(size_t)(k0 + kr + i * 16) * ld_src + n0 + nc];
        t[nc + 0][kr + i * 16] = (half_t)v.x;
        t[nc + 1][kr + i * 16] = (half_t)v.y;
        t[nc + 2][kr + i * 16] = (half_t)v.z;
        t[nc + 3][kr + i * 16] = (half_t)v.w;
    }
    __syncthreads();
    int nr = tid >> 2, kc = (tid & 3) * 16;
    f16x8_t w0 = *(const f16x8_t*)&t[nr][kc];
    f16x8_t w1 = *(const f16x8_t*)&t[nr][kc + 8];
    *(f16x8_t*)&dst[(size_t)(n0 + nr) * ld_dst + k0 + kc] = w0;
    *(f16x8_t*)&dst[(size_t)(n0 + nr) * ld_dst + k0 + kc + 8] = w1;
}

// ---------------- generic TN fp16 MFMA GEMM ----------------
template<bool F16OUT>
__global__ __launch_bounds__(256) void gemm_f16t(
    const half_t* __restrict__ A, int lda, long long sA,
    const half_t* __restrict__ Bt, int ldb, long long sB,
    void* __restrict__ Cv, int ldc, long long sC, int K)
{
    A  += (size_t)blockIdx.z * sA;
    Bt += (size_t)blockIdx.z * sB;
    const int bm = blockIdx.y * 64, bn = blockIdx.x * 64;

    __shared__ __align__(16) char lds[2][16384];

    const int tid = threadIdx.x, w = tid >> 6, lane = tid & 63;
    const int l15 = lane & 15, q = lane >> 4;
    const int wr = w >> 1, wc = w & 1;

    const half_t* gA[2];
    const half_t* gB[2];
    #pragma unroll
    for (int p = 0; p < 2; p++) {
        int c = p * 64 + lane;
        int rl = c >> 3;
        int sg = (c & 7) ^ (rl & 7);
        gA[p] = A  + (size_t)(bm + w * 16 + rl) * lda + sg * 8;
        gB[p] = Bt + (size_t)(bn + w * 16 + rl) * ldb + sg * 8;
    }

    f32x4_t acc[2][2];
    #pragma unroll
    for (int i = 0; i < 2; i++)
        #pragma unroll
        for (int j = 0; j < 2; j++) acc[i][j] = (f32x4_t){0.f, 0.f, 0.f, 0.f};

    const int nsteps = K >> 6;

    {
        char* ab = lds[0];
        char* bb = ab + 8192;
        #pragma unroll
        for (int p = 0; p < 2; p++) {
            gload_lds16(gA[p], ab + w * 2048 + p * 1024);
            gload_lds16(gB[p], bb + w * 2048 + p * 1024);
        }
    }
    __syncthreads();

    int cur = 0;
    for (int s = 0; s < nsteps; s++) {
        if (s + 1 < nsteps) {
            int k0 = (s + 1) << 6;
            char* ab = lds[cur ^ 1];
            char* bb = ab + 8192;
            #pragma unroll
            for (int p = 0; p < 2; p++) {
                gload_lds16(gA[p] + k0, ab + w * 2048 + p * 1024);
                gload_lds16(gB[p] + k0, bb + w * 2048 + p * 1024);
            }
        }
        {
            const char* ab = lds[cur];
            const char* bb = ab + 8192;
            #pragma unroll
            for (int kk = 0; kk < 2; kk++) {
                f16x8_t av[2], bv[2];
                #pragma unroll
                for (int i = 0; i < 2; i++) {
                    int ra = wr * 32 + i * 16 + l15;
                    av[i] = *(const f16x8_t*)(ab + ra * 128 + (((kk * 4 + q) ^ (ra & 7)) * 16));
                    int rb = wc * 32 + i * 16 + l15;
                    bv[i] = *(const f16x8_t*)(bb + rb * 128 + (((kk * 4 + q) ^ (rb & 7)) * 16));
                }
                #pragma unroll
                for (int i = 0; i < 2; i++)
                    #pragma unroll
                    for (int j = 0; j < 2; j++)
                        acc[i][j] = MFMA_F16(av[i], bv[j], acc[i][j]);
            }
        }
        __syncthreads();
        cur ^= 1;
    }

    half_t* Ch = (half_t*)Cv + (F16OUT ? (size_t)blockIdx.z * sC : 0);
    float*  Cf = (float*)Cv  + (F16OUT ? 0 : (size_t)blockIdx.z * sC);
    #pragma unroll
    for (int i = 0; i < 2; i++)
        #pragma unroll
        for (int j = 0; j < 2; j++)
            #pragma unroll
            for (int r = 0; r < 4; r++) {
                size_t row = bm + wr * 32 + i * 16 + q * 4 + r;
                size_t col = bn + wc * 32 + j * 16 + l15;
                if (F16OUT) Ch[row * ldc + col] = (half_t)acc[i][j][r];
                else        Cf[row * ldc + col] = acc[i][j][r];
            }
}

// ---------------- split attention: grid (M, SPLIT), 512 threads (8 waves) ----------------
// Each block: rows t in [sp*SROWS, (sp+1)*SROWS). Outputs UNNORMALIZED partial
// O (fp16) + per-head (max, sumexp) for cross-split merge.
__global__ __launch_bounds__(512) void attn_split(
    const half_t* __restrict__ qf,    // [M*16][576]
    const half_t* __restrict__ kvb,   // [4096][576]
    const int* __restrict__ indices,  // [M][512]
    half_t* __restrict__ op,          // [SPLIT][M*16][512]
    float2* __restrict__ ml)          // [SPLIT][M*16]
{
    const int m = blockIdx.x, sp = blockIdx.y;
    const int tid = threadIdx.x;
    const int w = tid >> 6, lane = tid & 63;
    const int l15 = lane & 15, q = lane >> 4;

    __shared__ __align__(16) char u_mem[32768];               // scores f32 [16][260] / V-tile [32][1024B]
    __shared__ __align__(16) unsigned short p_s[16 * SROWS];  // P fp16 bits, swizzled 512B rows

    float* s_s = (float*)u_mem;
    unsigned short* v_s = (unsigned short*)u_mem;

    const int* idxp = indices + (size_t)m * TOPK + sp * SROWS;

    // ---------- scores: wave w owns t-groups {2w, 2w+1} ----------
    int rows[2];
    rows[0] = idxp[(w * 2 + 0) * 16 + l15];
    rows[1] = idxp[(w * 2 + 1) * 16 + l15];

    f32x4_t acc[2];
    acc[0] = (f32x4_t){0.f, 0.f, 0.f, 0.f};
    acc[1] = (f32x4_t){0.f, 0.f, 0.f, 0.f};

    const half_t* qh = qf + ((size_t)m * 16 + l15) * D_ATT + q * 8;

    #pragma unroll 3
    for (int kk = 0; kk < 18; kk++) {
        f16x8_t ah = *(const f16x8_t*)(qh + kk * 32);
        #pragma unroll
        for (int tt = 0; tt < 2; tt++) {
            f16x8_t b = *(const f16x8_t*)(kvb + (size_t)rows[tt] * D_ATT + kk * 32 + q * 8);
            acc[tt] = MFMA_F16(ah, b, acc[tt]);
        }
    }

    const float scale = 1.0f / 24.0f;
    #pragma unroll
    for (int tt = 0; tt < 2; tt++) {
        int t = (w * 2 + tt) * 16 + l15;
        #pragma unroll
        for (int r = 0; r < 4; r++)
            s_s[(q * 4 + r) * 260 + t] = acc[tt][r] * scale;
    }
    __syncthreads();

    // ---------- softmax: 32 threads per head, unnormalized P ----------
    {
        int h = tid >> 5, j = tid & 31;
        float mx = -1e30f;
        #pragma unroll
        for (int t = j; t < SROWS; t += 32) mx = fmaxf(mx, s_s[h * 260 + t]);
        #pragma unroll
        for (int off = 16; off; off >>= 1) mx = fmaxf(mx, __shfl_xor(mx, off, 32));
        float sum = 0.f;
        #pragma unroll
        for (int t = j; t < SROWS; t += 32) {
            float e = __expf(s_s[h * 260 + t] - mx);
            sum += e;
            union { half_t hh; unsigned short u; } cv;
            cv.hh = (half_t)e;
            unsigned byte = ((unsigned)(t * 2)) ^ (((unsigned)(h & 7)) << 4);
            p_s[h * SROWS + (byte >> 1)] = cv.u;
        }
        #pragma unroll
        for (int off = 16; off; off >>= 1) sum += __shfl_xor(sum, off, 32);
        if (j == 0)
            ml[(size_t)sp * (M_DIM * H_DIM) + m * 16 + h] = make_float2(mx, sum);
    }
    __syncthreads();

    // ---------- PV: 8 tiles of 32 rows; wave w owns col-groups 4w..4w+3 ----------
    f32x4_t oacc[4];
    #pragma unroll
    for (int i = 0; i < 4; i++) oacc[i] = (f32x4_t){0.f, 0.f, 0.f, 0.f};

    const unsigned vbase = lds_addr32(v_s);
    const int trow = tid >> 4, jb4 = tid & 15;   // 32 rows x 16 chunk-threads (64B each)
    const unsigned swz_w = (((unsigned)(trow & 7)) << 4) ^ (((unsigned)((trow >> 3) & 3)) << 5);

    int rstage[8];
    #pragma unroll
    for (int ct = 0; ct < 8; ct++) rstage[ct] = idxp[ct * 32 + trow];

    const int row1 = q * 8 + (l15 >> 2);
    const int row2 = row1 + 4;
    const unsigned sw1 = (((unsigned)(row1 & 7)) << 4) ^ (((unsigned)q & 3u) << 5);
    const unsigned sw2 = (((unsigned)(row2 & 7)) << 4) ^ (((unsigned)q & 3u) << 5);
    const unsigned cbyte = (unsigned)((l15 & 3) * 8);

    #pragma unroll 1
    for (int ct = 0; ct < 8; ct++) {
        // stage V tile: 32 rows x 512 cols fp16, xor-swizzled 1024B rows
        {
            const half_t* src = kvb + (size_t)rstage[ct] * D_ATT + jb4 * 32;
            f16x8_t tmp[4];
            #pragma unroll
            for (int i = 0; i < 4; i++) tmp[i] = *(const f16x8_t*)(src + i * 8);
            #pragma unroll
            for (int i = 0; i < 4; i++) {
                unsigned byte = ((unsigned)(jb4 * 64 + i * 16)) ^ swz_w;
                *(f16x8_t*)((char*)v_s + trow * 1024 + byte) = tmp[i];
            }
        }
        __syncthreads();

        // A-frag: P[h=l15][ct*32 + q*8 .. +7]
        f16x8_t pa;
        {
            unsigned pbyte = ((unsigned)(ct * 64 + q * 16)) ^ (((unsigned)(l15 & 7)) << 4);
            pa = *(const f16x8_t*)((const char*)p_s + l15 * (SROWS * 2) + pbyte);
        }

        // B-frags via hardware transpose reads
        u32x2_t blo[4], bhi[4];
        #pragma unroll
        for (int i = 0; i < 4; i++) {
            unsigned c2 = ((unsigned)((w * 4 + i) * 32)) + cbyte;
            unsigned a1 = vbase + (unsigned)row1 * 1024u + (c2 ^ sw1);
            unsigned a2 = vbase + (unsigned)row2 * 1024u + (c2 ^ sw2);
            asm volatile("ds_read_b64_tr_b16 %0, %1 offset:0" : "=v"(blo[i]) : "v"(a1) : "memory");
            asm volatile("ds_read_b64_tr_b16 %0, %1 offset:0" : "=v"(bhi[i]) : "v"(a2) : "memory");
        }
        asm volatile("s_waitcnt lgkmcnt(0)" ::: "memory");
        __builtin_amdgcn_sched_barrier(0);

        __builtin_amdgcn_s_setprio(1);
        #pragma unroll
        for (int i = 0; i < 4; i++) {
            union { f16x8_t s; struct { u32x2_t lo, hi; } u; } f;
            f.u.lo = blo[i]; f.u.hi = bhi[i];
            oacc[i] = MFMA_F16(pa, f.s, oacc[i]);
        }
        __builtin_amdgcn_s_setprio(0);

        __syncthreads();
    }

    // write unnormalized partial O (fp16): row h = q*4+r, col c
    half_t* ob = op + ((size_t)sp * M_DIM + m) * (H_DIM * D_KV_C);
    #pragma unroll
    for (int i = 0; i < 4; i++) {
        int c = (w * 4 + i) * 16 + l15;
        #pragma unroll
        for (int r = 0; r < 4; r++)
            ob[(size_t)(q * 4 + r) * D_KV_C + c] = (half_t)oacc[i][r];
    }
}

// ---------------- merge the SPLIT partials ----------------
__global__ __launch_bounds__(256) void attn_merge(
    const half_t* __restrict__ op,   // [SPLIT][M*16][512]
    const float2* __restrict__ ml,   // [SPLIT][M*16]
    half_t* __restrict__ o)          // [M*16][512]
{
    int idx = blockIdx.x * 256 + threadIdx.x;
    if (idx >= M_DIM * H_DIM * D_KV_C / 8) return;
    int mh = idx >> 6;
    int c8 = (idx & 63) * 8;
    float2 a = ml[mh];
    float2 b = ml[M_DIM * H_DIM + mh];
    float Mx = fmaxf(a.x, b.x);
    float w0 = __expf(a.x - Mx), w1 = __expf(b.x - Mx);
    float inv = 1.0f / (w0 * a.y + w1 * b.y);
    w0 *= inv; w1 *= inv;
    f16x8_t v0 = *(const f16x8_t*)(op + (size_t)mh * D_KV_C + c8);
    f16x8_t v1 = *(const f16x8_t*)(op + ((size_t)(M_DIM * H_DIM) + mh) * D_KV_C + c8);
    f16x8_t o8;
    #pragma unroll
    for (int j = 0; j < 8; j++)
        o8[j] = (half_t)(w0 * (float)v0[j] + w1 * (float)v1[j]);
    *(f16x8_t*)(o + (size_t)mh * D_KV_C + c8) = o8;
}

// ---------------- launch ----------------
extern "C" void kernel_launch(void* const* d_in, const int* in_sizes, int n_in,
                              void* d_out, int out_size, void* d_ws, size_t ws_size,
                              hipStream_t stream)
{
    const float* x        = (const float*)d_in[0];
    const float* W_cqkv   = (const float*)d_in[1];
    const float* W_uq     = (const float*)d_in[2];
    const float* W_qk     = (const float*)d_in[3];
    const float* kv_cache = (const float*)d_in[4];
    const float* W_o1     = (const float*)d_in[5];
    const float* W_oproj  = (const float*)d_in[6];
    const int*   indices  = (const int*)d_in[7];
    float* out = (float*)d_out;

    // workspace layout (half_t units), lifetime-overlaid; peak ~89.7MB
    half_t* wsh = (half_t*)d_ws;
    half_t* Wcqkv_t = wsh;                      // [0, 11010048)  dead after gemm1
    half_t* qc16    = wsh;                      //   overlay after gemm1: [0, 786432), dead after gemm2
    half_t* o_part  = wsh;                      //   overlay at attn: [0, 8388608) = 2*512*16*512
    half_t* q32h    = wsh + 786432;             //   [786432, 7077888) fp32 x2 slices (dead after cvt_sum_q)
    half_t* q16     = wsh + 7077888;            //   [7077888, 8650752)... NOTE: overlaps o_part!
    half_t* x16     = wsh + 11010048;           // [11010048, 14680064), dead after gemm1
    half_t* o2_16   = wsh + 11010048;           //   overlay after attn-merge chain (gemm5 out)
    half_t* Wuq_t   = wsh + 14680064;           // [14680064, 19398656), dead after gemm2
    half_t* o16     = wsh + 14680064;           //   overlay: merge output
    half_t* Wqk_t   = wsh + 19398656;           // [19398656, 20447232), dead after gemm3
    half_t* ml_h    = wsh + 19398656;           //   overlay at attn: 2*8192 float2 = 131072 halves
    half_t* Wo1_t   = wsh + 20447232;           // [20447232, 21495808)
    half_t* Wop_t   = wsh + 21495808;           // [21495808, 36175872)
    half_t* kv16    = wsh + 36175872;           // [36175872, 38535168)
    half_t* qc32h   = wsh + 38535168;           // [38535168, 44826624) fp32 x4 slices
    half_t* qf16    = wsh + 38535168;           //   overlay after cvt_sum: [.., 43253760)
    float*  qc32 = (float*)qc32h;
    float*  q32  = (float*)q32h;
    float2* ml   = (float2*)ml_h;

    // q16 [7077888, 8650752) vs o_part [0, 8388608): q16 is dead after gemm3,
    // o_part written by attn (after gemm3) -> OK.

    // ---- conversions ----
    cvt_f16<<<(M_DIM * HID / 8 + 255) / 256, 256, 0, stream>>>(x, x16, M_DIM * HID / 8);
    cvt_f16<<<(S_KV * D_ATT / 8 + 255) / 256, 256, 0, stream>>>(kv_cache, kv16, S_KV * D_ATT / 8);
    cvt_t<<<dim3(D_Q_C / 64, HID / 64, 1), 256, 0, stream>>>(
        W_cqkv + D_KV_C, D_KV_C + D_Q_C + D_R, 0, Wcqkv_t, HID, 0);
    cvt_t<<<dim3(3072 / 64, D_Q_C / 64, 1), 256, 0, stream>>>(
        W_uq, 3072, 0, Wuq_t, D_Q_C, 0);
    cvt_t<<<dim3(D_KV_C / 64, D_Q / 64, H_DIM), 256, 0, stream>>>(
        W_qk, D_KV_C, D_Q * D_KV_C, Wqk_t, D_Q, D_Q * D_KV_C);
    cvt_t<<<dim3(D_KV / 64, D_KV_C / 64, H_DIM), 256, 0, stream>>>(
        W_o1, D_KV, D_KV_C * D_KV, Wo1_t, D_KV_C, D_KV_C * D_KV);
    cvt_t<<<dim3(HID / 64, 2048 / 64, 1), 256, 0, stream>>>(
        W_oproj, HID, 0, Wop_t, 2048, 0);

    // ---- GEMM chain ----
    // 1) qc32 slices = x16 @ Wcqkv_t^T, split-K x4
    gemm_f16t<false><<<dim3(D_Q_C / 64, M_DIM / 64, 4), 256, 0, stream>>>(
        x16, HID, 1792, Wcqkv_t, HID, 1792, qc32, D_Q_C, (long long)M_DIM * D_Q_C, 1792);
    cvt_sum<4><<<(M_DIM * D_Q_C / 8 + 255) / 256, 256, 0, stream>>>(
        qc32, (long long)M_DIM * D_Q_C, qc16, M_DIM * D_Q_C / 8);

    // 2) q32 slices = qc16 @ Wuq_t^T, split-K x2
    gemm_f16t<false><<<dim3(3072 / 64, M_DIM / 64, 2), 256, 0, stream>>>(
        qc16, D_Q_C, 768, Wuq_t, D_Q_C, 768, q32, 3072, (long long)M_DIM * 3072, 768);
    cvt_sum_q<<<(M_DIM * 3072 / 8 + 255) / 256, 256, 0, stream>>>(
        q32, (long long)M_DIM * 3072, q16, qf16);

    // 3) qf16[:, h, :512] = q_nope[:,h,:] @ Wqk_t[h]^T (batched z=16, K=128)
    gemm_f16t<true><<<dim3(D_KV_C / 64, M_DIM / 64, H_DIM), 256, 0, stream>>>(
        q16, 3072, D_Q + D_R, Wqk_t, D_Q, (long long)D_Q * D_KV_C,
        qf16, H_DIM * D_ATT, D_ATT, D_Q);

    // 4) split attention + merge
    attn_split<<<dim3(M_DIM, SPLIT), 512, 0, stream>>>(qf16, kv16, indices, o_part, ml);
    attn_merge<<<(M_DIM * H_DIM * D_KV_C / 8 + 255) / 256, 256, 0, stream>>>(o_part, ml, o16);

    // 5) o2 = o[:,h,:] @ Wo1_t[h]^T (batched z=16, K=512)
    gemm_f16t<true><<<dim3(D_KV / 64, M_DIM / 64, H_DIM), 256, 0, stream>>>(
        o16, H_DIM * D_KV_C, D_KV_C, Wo1_t, D_KV_C, (long long)D_KV_C * D_KV,
        o2_16, H_DIM * D_KV, D_KV, D_KV_C);

    // 6) out = o2 @ Wop_t^T (K=2048), fp32 out
    gemm_f16t<false><<<dim3(HID / 64, M_DIM / 64, 1), 256, 0, stream>>>(
        o2_16, H_DIM * D_KV, 0, Wop_t, 2048, 0, out, HID, 0, H_DIM * D_KV);
}

// Round 6
// 215.885 us; speedup vs baseline: 1.0319x; 1.0319x over previous
//
#include <hip/hip_runtime.h>
#include <hip/hip_bf16.h>

#define M_DIM 512
#define HID 7168
#define D_KV_C 512
#define D_Q_C 1536
#define D_R 64
#define D_Q 128
#define D_KV 128
#define H_DIM 16
#define S_KV 4096
#define TOPK 512
#define D_ATT 576
#define SPLIT 2
#define SROWS 256   // TOPK / SPLIT
#define SM_SCALE (1.0f / 24.0f)

typedef _Float16 half_t;
typedef __attribute__((ext_vector_type(8))) _Float16 f16x8_t;
typedef __attribute__((ext_vector_type(4))) float f32x4_t;
typedef __attribute__((ext_vector_type(2))) unsigned int u32x2_t;

#define MFMA_F16(a, b, c) __builtin_amdgcn_mfma_f32_16x16x32_f16((a), (b), (c), 0, 0, 0)

__device__ __forceinline__ unsigned lds_addr32(const void* p) {
    return (unsigned)(unsigned long long)(const __attribute__((address_space(3))) char*)p;
}

typedef const __attribute__((address_space(1))) unsigned int* gptr_t;
typedef __attribute__((address_space(3))) unsigned int* lptr_t;
__device__ __forceinline__ void gload_lds16(const void* g, void* l) {
    __builtin_amdgcn_global_load_lds((gptr_t)g, (lptr_t)l, 16, 0, 0);
}

// ---------------- elementwise fp32 -> fp16 ----------------
__global__ __launch_bounds__(256) void cvt_f16(const float* __restrict__ src,
                                               half_t* __restrict__ dst, int n8)
{
    int i = blockIdx.x * 256 + threadIdx.x;
    if (i >= n8) return;
    const float4* s = (const float4*)src + (size_t)i * 2;
    float4 a = s[0], b = s[1];
    f16x8_t o;
    o[0] = (half_t)a.x; o[1] = (half_t)a.y; o[2] = (half_t)a.z; o[3] = (half_t)a.w;
    o[4] = (half_t)b.x; o[5] = (half_t)b.y; o[6] = (half_t)b.z; o[7] = (half_t)b.w;
    *(f16x8_t*)(dst + (size_t)i * 8) = o;
}

// ---------------- sum NS fp32 slices -> fp16 ----------------
template<int NS>
__global__ __launch_bounds__(256) void cvt_sum(const float* __restrict__ src, long long slice,
                                               half_t* __restrict__ dst, int n8)
{
    int i = blockIdx.x * 256 + threadIdx.x;
    if (i >= n8) return;
    float a[8] = {};
    #pragma unroll
    for (int s = 0; s < NS; s++) {
        const float4* p = (const float4*)(src + (size_t)s * slice) + (size_t)i * 2;
        float4 u = p[0], v = p[1];
        a[0] += u.x; a[1] += u.y; a[2] += u.z; a[3] += u.w;
        a[4] += v.x; a[5] += v.y; a[6] += v.z; a[7] += v.w;
    }
    f16x8_t o;
    #pragma unroll
    for (int j = 0; j < 8; j++) o[j] = (half_t)a[j];
    *(f16x8_t*)(dst + (size_t)i * 8) = o;
}

// sum 2 slices of q (512x3072) -> q16; scatter pe cols (SCALED by 1/24) into qf16 tail
__global__ __launch_bounds__(256) void cvt_sum_q(const float* __restrict__ src, long long slice,
                                                 half_t* __restrict__ q16, half_t* __restrict__ qf)
{
    int i = blockIdx.x * 256 + threadIdx.x;
    if (i >= M_DIM * 3072 / 8) return;
    float a[8] = {};
    #pragma unroll
    for (int s = 0; s < 2; s++) {
        const float4* p = (const float4*)(src + (size_t)s * slice) + (size_t)i * 2;
        float4 u = p[0], v = p[1];
        a[0] += u.x; a[1] += u.y; a[2] += u.z; a[3] += u.w;
        a[4] += v.x; a[5] += v.y; a[6] += v.z; a[7] += v.w;
    }
    f16x8_t o;
    #pragma unroll
    for (int j = 0; j < 8; j++) o[j] = (half_t)a[j];
    *(f16x8_t*)(q16 + (size_t)i * 8) = o;
    int col = (i * 8) % 3072;
    int c = col % 192;                 // within-head col; blocks of 8 never straddle
    if (c >= 128) {
        int row = (i * 8) / 3072, h = col / 192;
        int mh = row * 16 + h;
        f16x8_t os;
        #pragma unroll
        for (int j = 0; j < 8; j++) os[j] = (half_t)(a[j] * SM_SCALE);
        *(f16x8_t*)(qf + (size_t)mh * D_ATT + D_KV_C + (c - 128)) = os;
    }
}

// ---------------- transpose-convert fp32 [K][ld] -> fp16 [N][K] ----------------
__global__ __launch_bounds__(256) void cvt_t(
    const float* __restrict__ src, int ld_src, long long sS,
    half_t* __restrict__ dst, int ld_dst, long long sD)
{
    src += (size_t)blockIdx.z * sS;
    dst += (size_t)blockIdx.z * sD;
    int k0 = blockIdx.y * 64, n0 = blockIdx.x * 64;
    __shared__ half_t t[64][80];
    int tid = threadIdx.x;
    int kr = tid >> 4, nc = (tid & 15) * 4;
    #pragma unroll
    for (int i = 0; i < 4; i++) {
        float4 v = *(const float4*)&src[(size_t)(k0 + kr + i * 16) * ld_src + n0 + nc];
        t[nc + 0][kr + i * 16] = (half_t)v.x;
        t[nc + 1][kr + i * 16] = (half_t)v.y;
        t[nc + 2][kr + i * 16] = (half_t)v.z;
        t[nc + 3][kr + i * 16] = (half_t)v.w;
    }
    __syncthreads();
    int nr = tid >> 2, kc = (tid & 3) * 16;
    f16x8_t w0 = *(const f16x8_t*)&t[nr][kc];
    f16x8_t w1 = *(const f16x8_t*)&t[nr][kc + 8];
    *(f16x8_t*)&dst[(size_t)(n0 + nr) * ld_dst + k0 + kc] = w0;
    *(f16x8_t*)&dst[(size_t)(n0 + nr) * ld_dst + k0 + kc + 8] = w1;
}

// ---------------- generic TN fp16 MFMA GEMM (epilogue alpha) ----------------
template<bool F16OUT>
__global__ __launch_bounds__(256) void gemm_f16t(
    const half_t* __restrict__ A, int lda, long long sA,
    const half_t* __restrict__ Bt, int ldb, long long sB,
    void* __restrict__ Cv, int ldc, long long sC, int K, float alpha)
{
    A  += (size_t)blockIdx.z * sA;
    Bt += (size_t)blockIdx.z * sB;
    const int bm = blockIdx.y * 64, bn = blockIdx.x * 64;

    __shared__ __align__(16) char lds[2][16384];

    const int tid = threadIdx.x, w = tid >> 6, lane = tid & 63;
    const int l15 = lane & 15, q = lane >> 4;
    const int wr = w >> 1, wc = w & 1;

    const half_t* gA[2];
    const half_t* gB[2];
    #pragma unroll
    for (int p = 0; p < 2; p++) {
        int c = p * 64 + lane;
        int rl = c >> 3;
        int sg = (c & 7) ^ (rl & 7);
        gA[p] = A  + (size_t)(bm + w * 16 + rl) * lda + sg * 8;
        gB[p] = Bt + (size_t)(bn + w * 16 + rl) * ldb + sg * 8;
    }

    f32x4_t acc[2][2];
    #pragma unroll
    for (int i = 0; i < 2; i++)
        #pragma unroll
        for (int j = 0; j < 2; j++) acc[i][j] = (f32x4_t){0.f, 0.f, 0.f, 0.f};

    const int nsteps = K >> 6;

    {
        char* ab = lds[0];
        char* bb = ab + 8192;
        #pragma unroll
        for (int p = 0; p < 2; p++) {
            gload_lds16(gA[p], ab + w * 2048 + p * 1024);
            gload_lds16(gB[p], bb + w * 2048 + p * 1024);
        }
    }
    __syncthreads();

    int cur = 0;
    for (int s = 0; s < nsteps; s++) {
        if (s + 1 < nsteps) {
            int k0 = (s + 1) << 6;
            char* ab = lds[cur ^ 1];
            char* bb = ab + 8192;
            #pragma unroll
            for (int p = 0; p < 2; p++) {
                gload_lds16(gA[p] + k0, ab + w * 2048 + p * 1024);
                gload_lds16(gB[p] + k0, bb + w * 2048 + p * 1024);
            }
        }
        {
            const char* ab = lds[cur];
            const char* bb = ab + 8192;
            #pragma unroll
            for (int kk = 0; kk < 2; kk++) {
                f16x8_t av[2], bv[2];
                #pragma unroll
                for (int i = 0; i < 2; i++) {
                    int ra = wr * 32 + i * 16 + l15;
                    av[i] = *(const f16x8_t*)(ab + ra * 128 + (((kk * 4 + q) ^ (ra & 7)) * 16));
                    int rb = wc * 32 + i * 16 + l15;
                    bv[i] = *(const f16x8_t*)(bb + rb * 128 + (((kk * 4 + q) ^ (rb & 7)) * 16));
                }
                #pragma unroll
                for (int i = 0; i < 2; i++)
                    #pragma unroll
                    for (int j = 0; j < 2; j++)
                        acc[i][j] = MFMA_F16(av[i], bv[j], acc[i][j]);
            }
        }
        __syncthreads();
        cur ^= 1;
    }

    half_t* Ch = (half_t*)Cv + (F16OUT ? (size_t)blockIdx.z * sC : 0);
    float*  Cf = (float*)Cv  + (F16OUT ? 0 : (size_t)blockIdx.z * sC);
    #pragma unroll
    for (int i = 0; i < 2; i++)
        #pragma unroll
        for (int j = 0; j < 2; j++)
            #pragma unroll
            for (int r = 0; r < 4; r++) {
                size_t row = bm + wr * 32 + i * 16 + q * 4 + r;
                size_t col = bn + wc * 32 + j * 16 + l15;
                float v = acc[i][j][r] * alpha;
                if (F16OUT) Ch[row * ldc + col] = (half_t)v;
                else        Cf[row * ldc + col] = v;
            }
}

// ---------------- split attention: grid (M, SPLIT), 512 threads (8 waves) ----------------
// qf is PRE-SCALED by 1/24. In-register softmax; PV staged via async global_load_lds
// with pre-swizzled global source (content: LDS[R][x] = Vrow[x ^ f(R)]).
__global__ __launch_bounds__(512, 4) void attn_split(
    const half_t* __restrict__ qf,    // [M*16][576], pre-scaled
    const half_t* __restrict__ kvb,   // [4096][576]
    const int* __restrict__ indices,  // [M][512]
    half_t* __restrict__ op,          // [SPLIT][M*16][512]
    float2* __restrict__ ml)          // [SPLIT][M*16]
{
    const int m = blockIdx.x, sp = blockIdx.y;
    const int tid = threadIdx.x;
    const int w = tid >> 6, lane = tid & 63;
    const int l15 = lane & 15, q = lane >> 4;

    __shared__ __align__(16) char vbuf[2][32768];         // V tiles [32][1024B], swizzled content
    __shared__ __align__(16) unsigned short p_s[16 * SROWS]; // P fp16 bits, swizzled 512B rows
    __shared__ float red_m[16][8];
    __shared__ float red_s[16][8];

    const int* idxp = indices + (size_t)m * TOPK + sp * SROWS;

    // ---- prologue: async-stage PV tile 0 (hides under scores) ----
    // wave w stages tile-rows R = 4w..4w+3; lane covers LDS byte 16*lane of row R,
    // sourced from global byte (16*lane) ^ f(R)  ->  LDS[R][x] = V[R][x^f(R)]
    {
        #pragma unroll
        for (int j = 0; j < 4; j++) {
            int R = 4 * w + j;
            int grow = idxp[R];
            unsigned swz = (((unsigned)(R & 7)) << 4) ^ (((unsigned)((R >> 3) & 3)) << 5);
            const char* src = (const char*)(kvb + (size_t)grow * D_ATT) + (((unsigned)(16 * lane)) ^ swz);
            gload_lds16(src, vbuf[0] + R * 1024);
        }
    }

    // ---- scores: wave w owns t-groups {2w, 2w+1}; fully unrolled, pipelined ----
    const int rows0 = idxp[(w * 2 + 0) * 16 + l15];
    const int rows1 = idxp[(w * 2 + 1) * 16 + l15];

    f32x4_t acc0 = (f32x4_t){0.f, 0.f, 0.f, 0.f};
    f32x4_t acc1 = (f32x4_t){0.f, 0.f, 0.f, 0.f};

    const half_t* qp  = qf  + ((size_t)m * 16 + l15) * D_ATT + q * 8;
    const half_t* kp0 = kvb + (size_t)rows0 * D_ATT + q * 8;
    const half_t* kp1 = kvb + (size_t)rows1 * D_ATT + q * 8;

    #pragma unroll
    for (int kk = 0; kk < 18; kk++) {
        f16x8_t ah = *(const f16x8_t*)(qp  + kk * 32);
        f16x8_t b0 = *(const f16x8_t*)(kp0 + kk * 32);
        f16x8_t b1 = *(const f16x8_t*)(kp1 + kk * 32);
        acc0 = MFMA_F16(ah, b0, acc0);
        acc1 = MFMA_F16(ah, b1, acc1);
    }

    // ---- in-register softmax (head h = q*4+r; t = (2w+tt)*16 + l15) ----
    float gm[4], e0[4], e1[4];
    #pragma unroll
    for (int r = 0; r < 4; r++) {
        float mx = fmaxf(acc0[r], acc1[r]);
        #pragma unroll
        for (int off = 8; off; off >>= 1) mx = fmaxf(mx, __shfl_xor(mx, off, 16));
        if (l15 == 0) red_m[q * 4 + r][w] = mx;
    }
    __syncthreads();
    #pragma unroll
    for (int r = 0; r < 4; r++) {
        int h = q * 4 + r;
        float mx = red_m[h][0];
        #pragma unroll
        for (int ww = 1; ww < 8; ww++) mx = fmaxf(mx, red_m[h][ww]);
        gm[r] = mx;
        e0[r] = __expf(acc0[r] - mx);
        e1[r] = __expf(acc1[r] - mx);
        float s = e0[r] + e1[r];
        #pragma unroll
        for (int off = 8; off; off >>= 1) s += __shfl_xor(s, off, 16);
        if (l15 == 0) red_s[h][w] = s;
    }
    __syncthreads();
    if (w == 0 && l15 == 0) {
        #pragma unroll
        for (int r = 0; r < 4; r++) {
            int h = q * 4 + r;
            float s = 0.f;
            #pragma unroll
            for (int ww = 0; ww < 8; ww++) s += red_s[h][ww];
            ml[(size_t)sp * (M_DIM * H_DIM) + m * 16 + h] = make_float2(gm[r], s);
        }
    }
    // write unnormalized P (fp16) swizzled: byte = (t*2) ^ ((h&7)<<4)
    #pragma unroll
    for (int r = 0; r < 4; r++) {
        int h = q * 4 + r;
        int t0 = (w * 2 + 0) * 16 + l15;
        int t1 = t0 + 16;
        union { half_t hh; unsigned short u; } c0, c1;
        c0.hh = (half_t)e0[r]; c1.hh = (half_t)e1[r];
        p_s[h * SROWS + ((((unsigned)(t0 * 2)) ^ (((unsigned)(h & 7)) << 4)) >> 1)] = c0.u;
        p_s[h * SROWS + ((((unsigned)(t1 * 2)) ^ (((unsigned)(h & 7)) << 4)) >> 1)] = c1.u;
    }
    __syncthreads();   // P visible; also drains each wave's tile-0 stage (implicit vmcnt(0))

    // ---- PV: 8 tiles of 32 rows; wave w owns col-frags 4w..4w+3 ----
    f32x4_t oacc[4];
    #pragma unroll
    for (int i = 0; i < 4; i++) oacc[i] = (f32x4_t){0.f, 0.f, 0.f, 0.f};

    const int row1 = q * 8 + (l15 >> 2);
    const int row2 = row1 + 4;
    const unsigned sw1 = (((unsigned)(row1 & 7)) << 4) ^ (((unsigned)((row1 >> 3) & 3)) << 5);
    const unsigned sw2 = (((unsigned)(row2 & 7)) << 4) ^ (((unsigned)((row2 >> 3) & 3)) << 5);
    const unsigned cbyte = (unsigned)((l15 & 3) * 8);

    #pragma unroll 1
    for (int ct = 0; ct < 8; ct++) {
        // issue next tile's async stage into the other buffer
        if (ct < 7) {
            #pragma unroll
            for (int j = 0; j < 4; j++) {
                int R = 4 * w + j;
                int grow = idxp[(ct + 1) * 32 + R];
                unsigned swz = (((unsigned)(R & 7)) << 4) ^ (((unsigned)((R >> 3) & 3)) << 5);
                const char* src = (const char*)(kvb + (size_t)grow * D_ATT) + (((unsigned)(16 * lane)) ^ swz);
                gload_lds16(src, vbuf[(ct + 1) & 1] + R * 1024);
            }
        }

        const unsigned vb = lds_addr32(vbuf[ct & 1]);

        // A-frag: P[h=l15][ct*32 + q*8 .. +7]
        f16x8_t pa;
        {
            unsigned pbyte = ((unsigned)(ct * 64 + q * 16)) ^ (((unsigned)(l15 & 7)) << 4);
            pa = *(const f16x8_t*)((const char*)p_s + l15 * (SROWS * 2) + pbyte);
        }

        // B-frags via hardware transpose reads
        u32x2_t blo[4], bhi[4];
        #pragma unroll
        for (int i = 0; i < 4; i++) {
            unsigned c2 = ((unsigned)((w * 4 + i) * 32)) + cbyte;
            unsigned a1 = vb + (unsigned)row1 * 1024u + (c2 ^ sw1);
            unsigned a2 = vb + (unsigned)row2 * 1024u + (c2 ^ sw2);
            asm volatile("ds_read_b64_tr_b16 %0, %1 offset:0" : "=v"(blo[i]) : "v"(a1) : "memory");
            asm volatile("ds_read_b64_tr_b16 %0, %1 offset:0" : "=v"(bhi[i]) : "v"(a2) : "memory");
        }
        asm volatile("s_waitcnt lgkmcnt(0)" ::: "memory");
        __builtin_amdgcn_sched_barrier(0);

        __builtin_amdgcn_s_setprio(1);
        #pragma unroll
        for (int i = 0; i < 4; i++) {
            union { f16x8_t s; struct { u32x2_t lo, hi; } u; } f;
            f.u.lo = blo[i]; f.u.hi = bhi[i];
            oacc[i] = MFMA_F16(pa, f.s, oacc[i]);
        }
        __builtin_amdgcn_s_setprio(0);

        __syncthreads();   // drains this iter's stage (vmcnt 0) + all waves done reading buf
    }

    // write unnormalized partial O (fp16): row h = q*4+r, col c
    half_t* ob = op + ((size_t)sp * M_DIM + m) * (H_DIM * D_KV_C);
    #pragma unroll
    for (int i = 0; i < 4; i++) {
        int c = (w * 4 + i) * 16 + l15;
        #pragma unroll
        for (int r = 0; r < 4; r++)
            ob[(size_t)(q * 4 + r) * D_KV_C + c] = (half_t)oacc[i][r];
    }
}

// ---------------- merge the SPLIT partials ----------------
__global__ __launch_bounds__(256) void attn_merge(
    const half_t* __restrict__ op,   // [SPLIT][M*16][512]
    const float2* __restrict__ ml,   // [SPLIT][M*16]
    half_t* __restrict__ o)          // [M*16][512]
{
    int idx = blockIdx.x * 256 + threadIdx.x;
    if (idx >= M_DIM * H_DIM * D_KV_C / 8) return;
    int mh = idx >> 6;
    int c8 = (idx & 63) * 8;
    float2 a = ml[mh];
    float2 b = ml[M_DIM * H_DIM + mh];
    float Mx = fmaxf(a.x, b.x);
    float w0 = __expf(a.x - Mx), w1 = __expf(b.x - Mx);
    float inv = 1.0f / (w0 * a.y + w1 * b.y);
    w0 *= inv; w1 *= inv;
    f16x8_t v0 = *(const f16x8_t*)(op + (size_t)mh * D_KV_C + c8);
    f16x8_t v1 = *(const f16x8_t*)(op + ((size_t)(M_DIM * H_DIM) + mh) * D_KV_C + c8);
    f16x8_t o8;
    #pragma unroll
    for (int j = 0; j < 8; j++)
        o8[j] = (half_t)(w0 * (float)v0[j] + w1 * (float)v1[j]);
    *(f16x8_t*)(o + (size_t)mh * D_KV_C + c8) = o8;
}

// ---------------- launch ----------------
extern "C" void kernel_launch(void* const* d_in, const int* in_sizes, int n_in,
                              void* d_out, int out_size, void* d_ws, size_t ws_size,
                              hipStream_t stream)
{
    const float* x        = (const float*)d_in[0];
    const float* W_cqkv   = (const float*)d_in[1];
    const float* W_uq     = (const float*)d_in[2];
    const float* W_qk     = (const float*)d_in[3];
    const float* kv_cache = (const float*)d_in[4];
    const float* W_o1     = (const float*)d_in[5];
    const float* W_oproj  = (const float*)d_in[6];
    const int*   indices  = (const int*)d_in[7];
    float* out = (float*)d_out;

    // workspace layout (half_t units), lifetime-overlaid; peak ~89.7MB
    half_t* wsh = (half_t*)d_ws;
    half_t* Wcqkv_t = wsh;                      // [0, 11010048)  dead after gemm1
    half_t* qc16    = wsh;                      //   overlay after gemm1
    half_t* o_part  = wsh;                      //   overlay at attn: [0, 8388608)
    half_t* q32h    = wsh + 786432;             //   [786432, 7077888) fp32 x2 slices
    half_t* q16     = wsh + 7077888;            //   [7077888, 8650752)
    half_t* x16     = wsh + 11010048;           // [11010048, 14680064)
    half_t* o2_16   = wsh + 11010048;           //   overlay after gemm5
    half_t* Wuq_t   = wsh + 14680064;           // [14680064, 19398656)
    half_t* o16     = wsh + 14680064;           //   overlay: merge output
    half_t* Wqk_t   = wsh + 19398656;           // [19398656, 20447232)
    half_t* ml_h    = wsh + 19398656;           //   overlay at attn
    half_t* Wo1_t   = wsh + 20447232;           // [20447232, 21495808)
    half_t* Wop_t   = wsh + 21495808;           // [21495808, 36175872)
    half_t* kv16    = wsh + 36175872;           // [36175872, 38535168)
    half_t* qc32h   = wsh + 38535168;           // [38535168, 44826624) fp32 x4 slices
    half_t* qf16    = wsh + 38535168;           //   overlay after cvt_sum
    float*  qc32 = (float*)qc32h;
    float*  q32  = (float*)q32h;
    float2* ml   = (float2*)ml_h;

    // ---- conversions ----
    cvt_f16<<<(M_DIM * HID / 8 + 255) / 256, 256, 0, stream>>>(x, x16, M_DIM * HID / 8);
    cvt_f16<<<(S_KV * D_ATT / 8 + 255) / 256, 256, 0, stream>>>(kv_cache, kv16, S_KV * D_ATT / 8);
    cvt_t<<<dim3(D_Q_C / 64, HID / 64, 1), 256, 0, stream>>>(
        W_cqkv + D_KV_C, D_KV_C + D_Q_C + D_R, 0, Wcqkv_t, HID, 0);
    cvt_t<<<dim3(3072 / 64, D_Q_C / 64, 1), 256, 0, stream>>>(
        W_uq, 3072, 0, Wuq_t, D_Q_C, 0);
    cvt_t<<<dim3(D_KV_C / 64, D_Q / 64, H_DIM), 256, 0, stream>>>(
        W_qk, D_KV_C, D_Q * D_KV_C, Wqk_t, D_Q, D_Q * D_KV_C);
    cvt_t<<<dim3(D_KV / 64, D_KV_C / 64, H_DIM), 256, 0, stream>>>(
        W_o1, D_KV, D_KV_C * D_KV, Wo1_t, D_KV_C, D_KV_C * D_KV);
    cvt_t<<<dim3(HID / 64, 2048 / 64, 1), 256, 0, stream>>>(
        W_oproj, HID, 0, Wop_t, 2048, 0);

    // ---- GEMM chain ----
    // 1) qc32 slices = x16 @ Wcqkv_t^T, split-K x4
    gemm_f16t<false><<<dim3(D_Q_C / 64, M_DIM / 64, 4), 256, 0, stream>>>(
        x16, HID, 1792, Wcqkv_t, HID, 1792, qc32, D_Q_C, (long long)M_DIM * D_Q_C, 1792, 1.0f);
    cvt_sum<4><<<(M_DIM * D_Q_C / 8 + 255) / 256, 256, 0, stream>>>(
        qc32, (long long)M_DIM * D_Q_C, qc16, M_DIM * D_Q_C / 8);

    // 2) q32 slices = qc16 @ Wuq_t^T, split-K x2
    gemm_f16t<false><<<dim3(3072 / 64, M_DIM / 64, 2), 256, 0, stream>>>(
        qc16, D_Q_C, 768, Wuq_t, D_Q_C, 768, q32, 3072, (long long)M_DIM * 3072, 768, 1.0f);
    cvt_sum_q<<<(M_DIM * 3072 / 8 + 255) / 256, 256, 0, stream>>>(
        q32, (long long)M_DIM * 3072, q16, qf16);

    // 3) qf16[:, h, :512] = (q_nope[:,h,:] @ Wqk_t[h]^T) * 1/24  (batched z=16, K=128)
    gemm_f16t<true><<<dim3(D_KV_C / 64, M_DIM / 64, H_DIM), 256, 0, stream>>>(
        q16, 3072, D_Q + D_R, Wqk_t, D_Q, (long long)D_Q * D_KV_C,
        qf16, H_DIM * D_ATT, D_ATT, D_Q, SM_SCALE);

    // 4) split attention + merge
    attn_split<<<dim3(M_DIM, SPLIT), 512, 0, stream>>>(qf16, kv16, indices, o_part, ml);
    attn_merge<<<(M_DIM * H_DIM * D_KV_C / 8 + 255) / 256, 256, 0, stream>>>(o_part, ml, o16);

    // 5) o2 = o[:,h,:] @ Wo1_t[h]^T (batched z=16, K=512)
    gemm_f16t<true><<<dim3(D_KV / 64, M_DIM / 64, H_DIM), 256, 0, stream>>>(
        o16, H_DIM * D_KV_C, D_KV_C, Wo1_t, D_KV_C, (long long)D_KV_C * D_KV,
        o2_16, H_DIM * D_KV, D_KV, D_KV_C, 1.0f);

    // 6) out = o2 @ Wop_t^T (K=2048), fp32 out
    gemm_f16t<false><<<dim3(HID / 64, M_DIM / 64, 1), 256, 0, stream>>>(
        o2_16, H_DIM * D_KV, 0, Wop_t, 2048, 0, out, HID, 0, 2048, 1.0f);
}